// Round 1
// baseline (483.787 us; speedup 1.0000x reference)
//
#include <hip/hip_runtime.h>
#include <math.h>

#define Bc 4
#define Nc 4000
#define Cc 80
#define Lc 81
#define NCc (Nc * Cc)            // 320000 per image
#define NBINS 16384
#define MCAP 4096
#define TARGET 2048
#define DET 100
#define BBOX_CLIPF 4.135166556742356f
#define BIN_BASE 0x3C000000u

// ---------- helpers ----------
__device__ __forceinline__ unsigned enc_f(float f) {
  unsigned u = __float_as_uint(f);
  return (u & 0x80000000u) ? ~u : (u | 0x80000000u);
}
__device__ __forceinline__ float dec_f(unsigned e) {
  unsigned u = (e & 0x80000000u) ? (e ^ 0x80000000u) : ~e;
  return __uint_as_float(u);
}

__device__ __forceinline__ void decode_box(const float* __restrict__ deltas,
                                           const float* __restrict__ props,
                                           int b, int i, float* o) {
  int n = i / Cc, c = i % Cc;
  int row = b * Nc + n;
  const float4 d = *reinterpret_cast<const float4*>(deltas + (size_t)row * (Cc * 4) + c * 4);
  const float4 p = *reinterpret_cast<const float4*>(props + (size_t)row * 4);
  float w = p.z - p.x, h = p.w - p.y;
  float cx = p.x + 0.5f * w, cy = p.y + 0.5f * h;
  float dw = fminf(d.z, BBOX_CLIPF), dh = fminf(d.w, BBOX_CLIPF);
  float pcx = d.x * w + cx, pcy = d.y * h + cy;
  float pw = expf(dw) * w, ph = expf(dh) * h;
  o[0] = pcx - 0.5f * pw;
  o[1] = pcy - 0.5f * ph;
  o[2] = pcx + 0.5f * pw;
  o[3] = pcy + 0.5f * ph;
}

// ---------- kernel A: per-row softmax stats (one wave per row) ----------
__global__ void row_stats_kernel(const float* __restrict__ logits,
                                 float* __restrict__ rowmax,
                                 float* __restrict__ rowsum) {
  int wave = threadIdx.x >> 6;
  int lane = threadIdx.x & 63;
  int row = blockIdx.x * 4 + wave;
  if (row >= Bc * Nc) return;
  const float* p = logits + (size_t)row * Lc;
  float v1 = p[lane];
  float v2 = (lane < Lc - 64) ? p[64 + lane] : -INFINITY;
  float m = fmaxf(v1, v2);
  #pragma unroll
  for (int o = 32; o; o >>= 1) m = fmaxf(m, __shfl_xor(m, o));
  float s = expf(v1 - m) + ((lane < Lc - 64) ? expf(v2 - m) : 0.0f);
  #pragma unroll
  for (int o = 32; o; o >>= 1) s += __shfl_xor(s, o);
  if (lane == 0) { rowmax[row] = m; rowsum[row] = s; }
}

// ---------- kernel B: scores, masked array, histogram, coord max ----------
__global__ void main_kernel(const float* __restrict__ logits,
                            const float* __restrict__ deltas,
                            const float* __restrict__ props,
                            const float* __restrict__ rowmax,
                            const float* __restrict__ rowsum,
                            float* __restrict__ msk,
                            unsigned* __restrict__ hist,
                            unsigned* __restrict__ maxb) {
  int t = blockIdx.x * blockDim.x + threadIdx.x;   // 0 .. B*NC-1
  int b = t / NCc;
  int i = t % NCc;                                  // NC % 256 == 0 -> b uniform per block
  int n = i / Cc, c = i % Cc;
  int row = b * Nc + n;

  float lg = logits[(size_t)row * Lc + (c + 1)];
  float score = expf(lg - rowmax[row]) / rowsum[row];

  float bb[4];
  decode_box(deltas, props, b, i, bb);
  float area = (bb[3] - bb[1]) * (bb[2] - bb[0]);
  bool valid = (score > 0.01f) && (area > 0.1f);
  msk[t] = valid ? score : -1.0f;

  if (valid) {
    unsigned bits = __float_as_uint(score);
    int bin = (int)((bits - BIN_BASE) >> 12);
    bin = bin < 0 ? 0 : (bin > NBINS - 1 ? NBINS - 1 : bin);
    atomicAdd(&hist[b * NBINS + bin], 1u);
  }

  // per-image coordinate max over ALL decoded boxes (for the label-offset)
  float mc = fmaxf(fmaxf(bb[0], bb[1]), fmaxf(bb[2], bb[3]));
  unsigned e = enc_f(mc);
  #pragma unroll
  for (int o = 32; o; o >>= 1) {
    unsigned other = __shfl_xor(e, o);
    e = e > other ? e : other;
  }
  if ((threadIdx.x & 63) == 0) atomicMax(&maxb[b], e);
}

// ---------- kernel C: select + sort + greedy NMS (1 block per image) ----------
__global__ void __launch_bounds__(1024)
nms_kernel(const float* __restrict__ deltas,
           const float* __restrict__ props,
           const float* __restrict__ msk,
           const unsigned* __restrict__ hist,
           const unsigned* __restrict__ maxb_enc,
           float* __restrict__ out) {
  const int b = blockIdx.x;
  const int tid = threadIdx.x;

  __shared__ unsigned long long keys[MCAP];   // 32 KB (first 4KB reused as scan buf)
  __shared__ float bx[1024][5];               // 20 KB: x1,y1,x2,y2,offc
  __shared__ float acc_box[DET][4];           // offset coords of accepted
  __shared__ float cb5[5];
  __shared__ int sh_Tbin, sh_selN, sh_flag, sh_acc;

  const unsigned* h = hist + (size_t)b * NBINS;
  float mb = dec_f(maxb_enc[b]);
  float off_scale = mb + 1.0f;

  // --- step 1: find threshold bin via suffix scan of 16-bin partials ---
  unsigned* sc = reinterpret_cast<unsigned*>(keys);   // sc[0..1023]
  unsigned psum = 0;
  #pragma unroll 4
  for (int k = 0; k < 16; ++k) psum += h[tid * 16 + k];
  sc[tid] = psum;
  __syncthreads();
  for (int o = 1; o < 1024; o <<= 1) {
    unsigned v = (tid + o < 1024) ? sc[tid + o] : 0u;
    __syncthreads();
    sc[tid] += v;
    __syncthreads();
  }
  unsigned suf = sc[tid];
  unsigned sufn = (tid < 1023) ? sc[tid + 1] : 0u;
  if (tid == 0 && sc[0] < TARGET) sh_Tbin = 0;        // few candidates: take all
  if (suf >= TARGET && sufn < TARGET) {               // unique crossing thread
    unsigned cum = sufn;
    int lo = tid * 16;
    for (int bin = lo + 15; bin >= lo; --bin) {
      cum += h[bin];
      if (cum >= TARGET) {
        int tb = bin;
        while (cum > MCAP) { cum -= h[tb]; ++tb; }    // pathological-tie guard
        sh_Tbin = tb;
        break;
      }
    }
  }
  __syncthreads();
  int Tbin = sh_Tbin;

  // --- step 2: compact candidates above threshold into keys ---
  if (tid == 0) sh_selN = 0;
  __syncthreads();
  const float* m = msk + (size_t)b * NCc;
  for (int i = tid; i < NCc; i += 1024) {
    float v = m[i];
    if (v > 0.0f) {
      unsigned bits = __float_as_uint(v);
      int bin = (int)((bits - BIN_BASE) >> 12);
      if (bin >= Tbin) {
        int pos = atomicAdd(&sh_selN, 1);
        if (pos < MCAP)
          keys[pos] = ((unsigned long long)(0xFFFFFFFFu - bits) << 32) | (unsigned)i;
      }
    }
  }
  __syncthreads();
  int S = sh_selN < MCAP ? sh_selN : MCAP;
  for (int i = S + tid; i < MCAP; i += 1024) keys[i] = ~0ULL;
  __syncthreads();

  // --- step 3: bitonic sort ascending (== score desc, index asc) ---
  for (int k = 2; k <= MCAP; k <<= 1) {
    for (int j = k >> 1; j > 0; j >>= 1) {
      __syncthreads();
      for (int idx = tid; idx < MCAP; idx += 1024) {
        int l = idx ^ j;
        if (l > idx) {
          unsigned long long a = keys[idx], c = keys[l];
          bool asc = ((idx & k) == 0);
          if (asc ? (a > c) : (a < c)) { keys[idx] = c; keys[l] = a; }
        }
      }
    }
  }
  __syncthreads();

  // --- step 4: decode the first min(S,1024) candidates into LDS ---
  int S1 = S < 1024 ? S : 1024;
  if (tid < S1) {
    unsigned long long key = keys[tid];
    unsigned i = (unsigned)(key & 0xFFFFFFFFu);
    float bb[4];
    decode_box(deltas, props, b, (int)i, bb);
    bx[tid][0] = bb[0]; bx[tid][1] = bb[1]; bx[tid][2] = bb[2]; bx[tid][3] = bb[3];
    bx[tid][4] = (float)((int)(i % Cc) + 1) * off_scale;
  }
  if (tid == 0) sh_acc = 0;
  __syncthreads();

  // --- step 5: sequential greedy NMS ---
  for (int j = 0; j < S; ++j) {
    if (sh_acc >= DET) break;
    const float* cb;
    if (j < 1024) {
      cb = bx[j];
    } else {
      if (tid == 0) {
        unsigned long long key = keys[j];
        unsigned i = (unsigned)(key & 0xFFFFFFFFu);
        float bb[4];
        decode_box(deltas, props, b, (int)i, bb);
        cb5[0] = bb[0]; cb5[1] = bb[1]; cb5[2] = bb[2]; cb5[3] = bb[3];
        cb5[4] = (float)((int)(i % Cc) + 1) * off_scale;
      }
      __syncthreads();
      cb = cb5;
    }
    if (tid == 0) sh_flag = 0;
    __syncthreads();
    int a = sh_acc;
    if (tid < a) {
      float o = cb[4];
      float ax1 = cb[0] + o, ay1 = cb[1] + o, ax2 = cb[2] + o, ay2 = cb[3] + o;
      float bx1 = acc_box[tid][0], by1 = acc_box[tid][1];
      float bx2 = acc_box[tid][2], by2 = acc_box[tid][3];
      float ix1 = fmaxf(ax1, bx1), iy1 = fmaxf(ay1, by1);
      float ix2 = fminf(ax2, bx2), iy2 = fminf(ay2, by2);
      float inter = fmaxf(ix2 - ix1, 0.0f) * fmaxf(iy2 - iy1, 0.0f);
      float a1 = (ax2 - ax1) * (ay2 - ay1);
      float a2 = (bx2 - bx1) * (by2 - by1);
      float iou = inter / (a1 + a2 - inter);
      if (iou > 0.5f) sh_flag = 1;
    }
    __syncthreads();
    if (tid == 0 && sh_flag == 0) {
      int a2i = sh_acc;
      float o = cb[4];
      acc_box[a2i][0] = cb[0] + o; acc_box[a2i][1] = cb[1] + o;
      acc_box[a2i][2] = cb[2] + o; acc_box[a2i][3] = cb[3] + o;
      unsigned long long key = keys[j];
      unsigned bits = 0xFFFFFFFFu - (unsigned)(key >> 32);
      unsigned i = (unsigned)(key & 0xFFFFFFFFu);
      out[(size_t)b * DET * 4 + a2i * 4 + 0] = cb[0];
      out[(size_t)b * DET * 4 + a2i * 4 + 1] = cb[1];
      out[(size_t)b * DET * 4 + a2i * 4 + 2] = cb[2];
      out[(size_t)b * DET * 4 + a2i * 4 + 3] = cb[3];
      out[Bc * DET * 4 + b * DET + a2i] = __uint_as_float(bits);
      out[Bc * DET * 4 + Bc * DET + b * DET + a2i] = (float)((int)(i % Cc) + 1);
      sh_acc = a2i + 1;
    }
    __syncthreads();
  }

  // --- step 6: zero-fill remaining slots (required: out not re-zeroed between replays) ---
  __syncthreads();
  int afin = sh_acc;
  for (int s = afin + tid; s < DET; s += 1024) {
    out[(size_t)b * DET * 4 + s * 4 + 0] = 0.0f;
    out[(size_t)b * DET * 4 + s * 4 + 1] = 0.0f;
    out[(size_t)b * DET * 4 + s * 4 + 2] = 0.0f;
    out[(size_t)b * DET * 4 + s * 4 + 3] = 0.0f;
    out[Bc * DET * 4 + b * DET + s] = 0.0f;
    out[Bc * DET * 4 + Bc * DET + b * DET + s] = 0.0f;
  }
}

// ---------- launch ----------
extern "C" void kernel_launch(void* const* d_in, const int* in_sizes, int n_in,
                              void* d_out, int out_size, void* d_ws, size_t ws_size,
                              hipStream_t stream) {
  const float* logits = (const float*)d_in[0];   // (B*N, 81)
  const float* deltas = (const float*)d_in[1];   // (B*N, 320)
  const float* props  = (const float*)d_in[2];   // (B, N, 4)
  float* out = (float*)d_out;

  char* ws = (char*)d_ws;
  unsigned* hist = (unsigned*)(ws + 0);              // B*NBINS*4 = 262144 B
  unsigned* maxb = (unsigned*)(ws + 262144);         // 16 B (padded)
  float* rowmax  = (float*)(ws + 262400);            // 64000 B
  float* rowsum  = (float*)(ws + 326400);            // 64000 B
  float* msk     = (float*)(ws + 390400);            // 5,120,000 B

  hipMemsetAsync(ws, 0, 262400, stream);             // hist + maxb

  row_stats_kernel<<<(Bc * Nc) / 4, 256, 0, stream>>>(logits, rowmax, rowsum);
  main_kernel<<<(Bc * NCc) / 256, 256, 0, stream>>>(logits, deltas, props,
                                                    rowmax, rowsum, msk, hist, maxb);
  nms_kernel<<<Bc, 1024, 0, stream>>>(deltas, props, msk, hist, maxb, out);
}

// Round 2
// 203.908 us; speedup vs baseline: 2.3726x; 2.3726x over previous
//
#include <hip/hip_runtime.h>
#include <math.h>

#define Bc 4
#define Nc 4000
#define Cc 80
#define Lc 81
#define NCc (Nc * Cc)            // 320000 per image
#define NBINS 16384
#define MCAP 2048
#define TARGET 1024
#define DET 100
#define BLKS_PER_IMG 1250        // NCc / 256
#define BBOX_CLIPF 4.135166556742356f
#define BIN_BASE 0x3C000000u

// ---------- helpers ----------
__device__ __forceinline__ unsigned enc_f(float f) {
  unsigned u = __float_as_uint(f);
  return (u & 0x80000000u) ? ~u : (u | 0x80000000u);
}
__device__ __forceinline__ float dec_f(unsigned e) {
  unsigned u = (e & 0x80000000u) ? (e ^ 0x80000000u) : ~e;
  return __uint_as_float(u);
}

__device__ __forceinline__ void decode_box(const float* __restrict__ deltas,
                                           const float* __restrict__ props,
                                           int b, int i, float* o) {
  int n = i / Cc, c = i % Cc;
  int row = b * Nc + n;
  const float4 d = *reinterpret_cast<const float4*>(deltas + (size_t)row * (Cc * 4) + c * 4);
  const float4 p = *reinterpret_cast<const float4*>(props + (size_t)row * 4);
  float w = p.z - p.x, h = p.w - p.y;
  float cx = p.x + 0.5f * w, cy = p.y + 0.5f * h;
  float dw = fminf(d.z, BBOX_CLIPF), dh = fminf(d.w, BBOX_CLIPF);
  float pcx = d.x * w + cx, pcy = d.y * h + cy;
  float pw = expf(dw) * w, ph = expf(dh) * h;
  o[0] = pcx - 0.5f * pw;
  o[1] = pcy - 0.5f * ph;
  o[2] = pcx + 0.5f * pw;
  o[3] = pcy + 0.5f * ph;
}

// ---------- kernel A: per-row softmax stats (one wave per row) ----------
__global__ void row_stats_kernel(const float* __restrict__ logits,
                                 float* __restrict__ rowmax,
                                 float* __restrict__ rowsum) {
  int wave = threadIdx.x >> 6;
  int lane = threadIdx.x & 63;
  int row = blockIdx.x * 4 + wave;
  if (row >= Bc * Nc) return;
  const float* p = logits + (size_t)row * Lc;
  float v1 = p[lane];
  float v2 = (lane < Lc - 64) ? p[64 + lane] : -INFINITY;
  float m = fmaxf(v1, v2);
  #pragma unroll
  for (int o = 32; o; o >>= 1) m = fmaxf(m, __shfl_xor(m, o));
  float s = expf(v1 - m) + ((lane < Lc - 64) ? expf(v2 - m) : 0.0f);
  #pragma unroll
  for (int o = 32; o; o >>= 1) s += __shfl_xor(s, o);
  if (lane == 0) { rowmax[row] = m; rowsum[row] = s; }
}

// ---------- kernel B: scores, masked array, histogram, per-block coord max ----------
__global__ void main_kernel(const float* __restrict__ logits,
                            const float* __restrict__ deltas,
                            const float* __restrict__ props,
                            const float* __restrict__ rowmax,
                            const float* __restrict__ rowsum,
                            float* __restrict__ msk,
                            unsigned* __restrict__ hist,
                            unsigned* __restrict__ blkmax) {
  int t = blockIdx.x * blockDim.x + threadIdx.x;   // 0 .. B*NC-1
  int b = t / NCc;
  int i = t % NCc;                                  // NC % 256 == 0 -> b uniform per block
  int n = i / Cc, c = i % Cc;
  int row = b * Nc + n;

  float lg = logits[(size_t)row * Lc + (c + 1)];
  float score = expf(lg - rowmax[row]) / rowsum[row];

  float bb[4];
  decode_box(deltas, props, b, i, bb);
  float area = (bb[3] - bb[1]) * (bb[2] - bb[0]);
  bool valid = (score > 0.01f) && (area > 0.1f);
  msk[t] = valid ? score : -1.0f;

  if (valid) {
    unsigned bits = __float_as_uint(score);
    int bin = (int)((bits - BIN_BASE) >> 12);
    bin = bin < 0 ? 0 : (bin > NBINS - 1 ? NBINS - 1 : bin);
    atomicAdd(&hist[b * NBINS + bin], 1u);
  }

  // per-image coordinate max over ALL decoded boxes: block-reduce, plain store
  float mc = fmaxf(fmaxf(bb[0], bb[1]), fmaxf(bb[2], bb[3]));
  unsigned e = enc_f(mc);
  #pragma unroll
  for (int o = 32; o; o >>= 1) {
    unsigned other = __shfl_xor(e, o);
    e = e > other ? e : other;
  }
  __shared__ unsigned wmax[4];
  if ((threadIdx.x & 63) == 0) wmax[threadIdx.x >> 6] = e;
  __syncthreads();
  if (threadIdx.x == 0) {
    unsigned m0 = wmax[0] > wmax[1] ? wmax[0] : wmax[1];
    unsigned m1 = wmax[2] > wmax[3] ? wmax[2] : wmax[3];
    blkmax[blockIdx.x] = m0 > m1 ? m0 : m1;
  }
}

// ---------- kernel C: select + sort + greedy NMS (1 block per image) ----------
__global__ void __launch_bounds__(1024)
nms_kernel(const float* __restrict__ deltas,
           const float* __restrict__ props,
           const float* __restrict__ msk,
           const unsigned* __restrict__ hist,
           const unsigned* __restrict__ blkmax,
           float* __restrict__ out) {
  const int b = blockIdx.x;
  const int tid = threadIdx.x;

  __shared__ unsigned long long keys[MCAP];   // 16 KB (first 4KB reused as scan buf)
  __shared__ float bx[MCAP][5];               // 40 KB: x1,y1,x2,y2,off
  __shared__ float sh_off;
  __shared__ int sh_Tbin, sh_selN;

  unsigned* sc = reinterpret_cast<unsigned*>(keys);   // sc[0..1023]

  // --- step 0: reduce per-block coordinate maxes -> off_scale ---
  unsigned e = 0;
  for (int i = b * BLKS_PER_IMG + tid; i < (b + 1) * BLKS_PER_IMG; i += 1024)
    e = e > blkmax[i] ? e : blkmax[i];
  sc[tid] = e;
  __syncthreads();
  #pragma unroll
  for (int o = 512; o; o >>= 1) {
    if (tid < o) { unsigned v = sc[tid + o]; if (v > sc[tid]) sc[tid] = v; }
    __syncthreads();
  }
  if (tid == 0) sh_off = dec_f(sc[0]) + 1.0f;
  __syncthreads();
  const float off_scale = sh_off;

  // --- step 1: find threshold bin via suffix scan of 16-bin partials ---
  const unsigned* h = hist + (size_t)b * NBINS;
  unsigned psum = 0;
  #pragma unroll 4
  for (int k = 0; k < 16; ++k) psum += h[tid * 16 + k];
  sc[tid] = psum;
  __syncthreads();
  for (int o = 1; o < 1024; o <<= 1) {
    unsigned v = (tid + o < 1024) ? sc[tid + o] : 0u;
    __syncthreads();
    sc[tid] += v;
    __syncthreads();
  }
  unsigned suf = sc[tid];
  unsigned sufn = (tid < 1023) ? sc[tid + 1] : 0u;
  if (tid == 0 && sc[0] < TARGET) sh_Tbin = 0;        // few candidates: take all
  if (suf >= TARGET && sufn < TARGET) {               // unique crossing thread
    unsigned cum = sufn;
    int lo = tid * 16;
    for (int bin = lo + 15; bin >= lo; --bin) {
      cum += h[bin];
      if (cum >= TARGET) {
        int tb = bin;
        while (cum > MCAP) { cum -= h[tb]; ++tb; }    // pathological-tie guard
        sh_Tbin = tb;
        break;
      }
    }
  }
  if (tid == 0) sh_selN = 0;
  __syncthreads();
  int Tbin = sh_Tbin;

  // --- step 2: compact candidates above threshold into keys (float4 loads) ---
  const float4* m4 = reinterpret_cast<const float4*>(msk + (size_t)b * NCc);
  const int NV4 = NCc / 4;                            // 80000
  for (int i4 = tid; i4 < NV4; i4 += 1024) {
    float4 v = m4[i4];
    float vv[4] = {v.x, v.y, v.z, v.w};
    #pragma unroll
    for (int q = 0; q < 4; ++q) {
      float s1 = vv[q];
      if (s1 > 0.0f) {
        unsigned bits = __float_as_uint(s1);
        int bin = (int)((bits - BIN_BASE) >> 12);
        bin = bin < 0 ? 0 : (bin > NBINS - 1 ? NBINS - 1 : bin);
        if (bin >= Tbin) {
          int pos = atomicAdd(&sh_selN, 1);
          if (pos < MCAP)
            keys[pos] = ((unsigned long long)(0xFFFFFFFFu - bits) << 32) | (unsigned)(i4 * 4 + q);
        }
      }
    }
  }
  __syncthreads();
  int S = sh_selN < MCAP ? sh_selN : MCAP;
  for (int i = S + tid; i < MCAP; i += 1024) keys[i] = ~0ULL;
  __syncthreads();

  // --- step 3: bitonic sort ascending (== score desc, index asc) ---
  for (int k = 2; k <= MCAP; k <<= 1) {
    for (int j = k >> 1; j > 0; j >>= 1) {
      for (int idx = tid; idx < MCAP; idx += 1024) {
        int l = idx ^ j;
        if (l > idx) {
          unsigned long long a = keys[idx], c = keys[l];
          bool asc = ((idx & k) == 0);
          if (asc ? (a > c) : (a < c)) { keys[idx] = c; keys[l] = a; }
        }
      }
      __syncthreads();
    }
  }

  // --- step 4: decode all S candidates into LDS ---
  for (int j = tid; j < S; j += 1024) {
    unsigned long long key = keys[j];
    unsigned i = (unsigned)(key & 0xFFFFFFFFu);
    float bb[4];
    decode_box(deltas, props, b, (int)i, bb);
    bx[j][0] = bb[0]; bx[j][1] = bb[1]; bx[j][2] = bb[2]; bx[j][3] = bb[3];
    bx[j][4] = (float)((int)(i % Cc) + 1) * off_scale;
  }
  __syncthreads();

  // --- step 5: sequential greedy NMS, 1 barrier/iter, accepted boxes in regs ---
  int acnt = 0;
  float rx1 = 0.f, ry1 = 0.f, rx2 = 0.f, ry2 = 0.f;   // my accepted (offset) box
  for (int j = 0; j < S && acnt < DET; ++j) {
    float c0 = bx[j][0], c1 = bx[j][1], c2 = bx[j][2], c3 = bx[j][3], co = bx[j][4];
    int flag = 0;
    if (tid < acnt) {
      float ax1 = c0 + co, ay1 = c1 + co, ax2 = c2 + co, ay2 = c3 + co;
      float ix1 = fmaxf(ax1, rx1), iy1 = fmaxf(ay1, ry1);
      float ix2 = fminf(ax2, rx2), iy2 = fminf(ay2, ry2);
      float inter = fmaxf(ix2 - ix1, 0.0f) * fmaxf(iy2 - iy1, 0.0f);
      float a1 = (ax2 - ax1) * (ay2 - ay1);
      float a2 = (rx2 - rx1) * (ry2 - ry1);
      flag = (inter / (a1 + a2 - inter)) > 0.5f;
    }
    int sup = __syncthreads_or(flag);
    if (!sup) {
      if (tid == acnt) { rx1 = c0 + co; ry1 = c1 + co; rx2 = c2 + co; ry2 = c3 + co; }
      if (tid == 0) {
        unsigned long long key = keys[j];
        unsigned bits = 0xFFFFFFFFu - (unsigned)(key >> 32);
        unsigned i = (unsigned)(key & 0xFFFFFFFFu);
        float* ob = out + (size_t)b * DET * 4 + acnt * 4;
        ob[0] = c0; ob[1] = c1; ob[2] = c2; ob[3] = c3;
        out[Bc * DET * 4 + b * DET + acnt] = __uint_as_float(bits);
        out[Bc * DET * 4 + Bc * DET + b * DET + acnt] = (float)((int)(i % Cc) + 1);
      }
      ++acnt;
    }
  }

  // --- step 6: zero-fill remaining slots (out not re-zeroed between replays) ---
  for (int s = acnt + tid; s < DET; s += 1024) {
    float* ob = out + (size_t)b * DET * 4 + s * 4;
    ob[0] = 0.0f; ob[1] = 0.0f; ob[2] = 0.0f; ob[3] = 0.0f;
    out[Bc * DET * 4 + b * DET + s] = 0.0f;
    out[Bc * DET * 4 + Bc * DET + b * DET + s] = 0.0f;
  }
}

// ---------- launch ----------
extern "C" void kernel_launch(void* const* d_in, const int* in_sizes, int n_in,
                              void* d_out, int out_size, void* d_ws, size_t ws_size,
                              hipStream_t stream) {
  const float* logits = (const float*)d_in[0];   // (B*N, 81)
  const float* deltas = (const float*)d_in[1];   // (B*N, 320)
  const float* props  = (const float*)d_in[2];   // (B, N, 4)
  float* out = (float*)d_out;

  char* ws = (char*)d_ws;
  unsigned* hist   = (unsigned*)(ws + 0);            // B*NBINS*4 = 262144 B
  unsigned* blkmax = (unsigned*)(ws + 262144);       // 5000*4 = 20000 B
  float* rowmax    = (float*)(ws + 282144);          // 64000 B
  float* rowsum    = (float*)(ws + 346144);          // 64000 B
  float* msk       = (float*)(ws + 410144);          // 5,120,000 B

  hipMemsetAsync(hist, 0, Bc * NBINS * 4, stream);

  row_stats_kernel<<<(Bc * Nc) / 4, 256, 0, stream>>>(logits, rowmax, rowsum);
  main_kernel<<<(Bc * NCc) / 256, 256, 0, stream>>>(logits, deltas, props,
                                                    rowmax, rowsum, msk, hist, blkmax);
  nms_kernel<<<Bc, 1024, 0, stream>>>(deltas, props, msk, hist, blkmax, out);
}

// Round 3
// 160.095 us; speedup vs baseline: 3.0219x; 1.2737x over previous
//
#include <hip/hip_runtime.h>
#include <math.h>

typedef unsigned long long ull;

#define Bc 4
#define Nc 4000
#define Cc 80
#define Lc 81
#define NCc (Nc * Cc)            // 320000 per image
#define NBINS 16384
#define MCAP 2048
#define TARGET 1024
#define DET 100
#define MBLK 1250                // main_kernel blocks per image
#define CBLK 313                 // compact blocks per image: ceil(80000/256)
#define BBOX_CLIPF 4.135166556742356f
#define BIN_BASE 0x3C000000u

// ---------- helpers ----------
__device__ __forceinline__ unsigned enc_f(float f) {
  unsigned u = __float_as_uint(f);
  return (u & 0x80000000u) ? ~u : (u | 0x80000000u);
}
__device__ __forceinline__ float dec_f(unsigned e) {
  unsigned u = (e & 0x80000000u) ? (e ^ 0x80000000u) : ~e;
  return __uint_as_float(u);
}

__device__ __forceinline__ void decode_box(const float* __restrict__ deltas,
                                           const float* __restrict__ props,
                                           int b, int i, float* o) {
  int n = i / Cc, c = i % Cc;
  int row = b * Nc + n;
  const float4 d = *reinterpret_cast<const float4*>(deltas + (size_t)row * (Cc * 4) + c * 4);
  const float4 p = *reinterpret_cast<const float4*>(props + (size_t)row * 4);
  float w = p.z - p.x, h = p.w - p.y;
  float cx = p.x + 0.5f * w, cy = p.y + 0.5f * h;
  float dw = fminf(d.z, BBOX_CLIPF), dh = fminf(d.w, BBOX_CLIPF);
  float pcx = d.x * w + cx, pcy = d.y * h + cy;
  float pw = expf(dw) * w, ph = expf(dh) * h;
  o[0] = pcx - 0.5f * pw;
  o[1] = pcy - 0.5f * ph;
  o[2] = pcx + 0.5f * pw;
  o[3] = pcy + 0.5f * ph;
}

// ---------- kernel 1: per-row softmax stats (one wave per row) ----------
__global__ void row_stats_kernel(const float* __restrict__ logits,
                                 float* __restrict__ rowmax,
                                 float* __restrict__ rowsum) {
  int wave = threadIdx.x >> 6;
  int lane = threadIdx.x & 63;
  int row = blockIdx.x * 4 + wave;
  if (row >= Bc * Nc) return;
  const float* p = logits + (size_t)row * Lc;
  float v1 = p[lane];
  float v2 = (lane < Lc - 64) ? p[64 + lane] : -INFINITY;
  float m = fmaxf(v1, v2);
  #pragma unroll
  for (int o = 32; o; o >>= 1) m = fmaxf(m, __shfl_xor(m, o));
  float s = expf(v1 - m) + ((lane < Lc - 64) ? expf(v2 - m) : 0.0f);
  #pragma unroll
  for (int o = 32; o; o >>= 1) s += __shfl_xor(s, o);
  if (lane == 0) { rowmax[row] = m; rowsum[row] = s; }
}

// ---------- kernel 2: scores, masked array, histogram, per-block coord max ----------
__global__ void main_kernel(const float* __restrict__ logits,
                            const float* __restrict__ deltas,
                            const float* __restrict__ props,
                            const float* __restrict__ rowmax,
                            const float* __restrict__ rowsum,
                            float* __restrict__ msk,
                            unsigned* __restrict__ hist,
                            unsigned* __restrict__ blkmax) {
  int t = blockIdx.x * blockDim.x + threadIdx.x;   // 0 .. B*NC-1
  int b = t / NCc;
  int i = t % NCc;                                  // NC % 256 == 0 -> b uniform per block
  int n = i / Cc, c = i % Cc;
  int row = b * Nc + n;

  float lg = logits[(size_t)row * Lc + (c + 1)];
  float score = expf(lg - rowmax[row]) / rowsum[row];

  float bb[4];
  decode_box(deltas, props, b, i, bb);
  float area = (bb[3] - bb[1]) * (bb[2] - bb[0]);
  bool valid = (score > 0.01f) && (area > 0.1f);
  msk[t] = valid ? score : -1.0f;

  if (valid) {
    unsigned bits = __float_as_uint(score);
    int bin = (int)((bits - BIN_BASE) >> 12);
    bin = bin < 0 ? 0 : (bin > NBINS - 1 ? NBINS - 1 : bin);
    atomicAdd(&hist[b * NBINS + bin], 1u);
  }

  float mc = fmaxf(fmaxf(bb[0], bb[1]), fmaxf(bb[2], bb[3]));
  unsigned e = enc_f(mc);
  #pragma unroll
  for (int o = 32; o; o >>= 1) {
    unsigned other = __shfl_xor(e, o);
    e = e > other ? e : other;
  }
  __shared__ unsigned wmax[4];
  if ((threadIdx.x & 63) == 0) wmax[threadIdx.x >> 6] = e;
  __syncthreads();
  if (threadIdx.x == 0) {
    unsigned m0 = wmax[0] > wmax[1] ? wmax[0] : wmax[1];
    unsigned m1 = wmax[2] > wmax[3] ? wmax[2] : wmax[3];
    blkmax[blockIdx.x] = m0 > m1 ? m0 : m1;
  }
}

// ---------- kernel 3: per-image off_scale + threshold bin ----------
__global__ void __launch_bounds__(1024)
tbin_kernel(const unsigned* __restrict__ hist,
            const unsigned* __restrict__ blkmax,
            unsigned* __restrict__ cnt,
            int* __restrict__ tbinp,
            float* __restrict__ offs) {
  const int b = blockIdx.x, tid = threadIdx.x;
  __shared__ unsigned sc[1024];
  __shared__ int sh_Tbin;

  unsigned e = 0;
  for (int i = tid; i < MBLK; i += 1024) {
    unsigned v = blkmax[b * MBLK + i];
    if (v > e) e = v;
  }
  sc[tid] = e;
  __syncthreads();
  #pragma unroll
  for (int o = 512; o; o >>= 1) {
    if (tid < o) { unsigned v = sc[tid + o]; if (v > sc[tid]) sc[tid] = v; }
    __syncthreads();
  }
  if (tid == 0) {
    offs[b] = dec_f(sc[0]) + 1.0f;
    cnt[b * 16] = 0;
  }
  __syncthreads();

  const unsigned* h = hist + (size_t)b * NBINS;
  unsigned psum = 0;
  #pragma unroll 4
  for (int k = 0; k < 16; ++k) psum += h[tid * 16 + k];
  sc[tid] = psum;
  __syncthreads();
  for (int o = 1; o < 1024; o <<= 1) {
    unsigned v = (tid + o < 1024) ? sc[tid + o] : 0u;
    __syncthreads();
    sc[tid] += v;
    __syncthreads();
  }
  unsigned suf = sc[tid];
  unsigned sufn = (tid < 1023) ? sc[tid + 1] : 0u;
  if (tid == 0 && sc[0] < TARGET) sh_Tbin = 0;
  if (suf >= TARGET && sufn < TARGET) {
    unsigned cum = sufn;
    int lo = tid * 16;
    for (int bin = lo + 15; bin >= lo; --bin) {
      cum += h[bin];
      if (cum >= TARGET) {
        int tb = bin;
        while (cum > MCAP) { cum -= h[tb]; ++tb; }   // pathological-tie guard
        sh_Tbin = tb;
        break;
      }
    }
  }
  __syncthreads();
  if (tid == 0) tbinp[b] = sh_Tbin;
}

// ---------- kernel 4: grid-wide compaction with wave-aggregated atomics ----------
__global__ void __launch_bounds__(256)
compact_kernel(const float* __restrict__ msk,
               const int* __restrict__ tbinp,
               unsigned* __restrict__ cnt,
               ull* __restrict__ keysg) {
  const int b = blockIdx.x / CBLK;
  const int loc = blockIdx.x % CBLK;
  const int i4 = loc * 256 + threadIdx.x;
  const int lane = threadIdx.x & 63;
  const int Tbin = tbinp[b];
  float4 v = make_float4(-1.f, -1.f, -1.f, -1.f);
  if (i4 < NCc / 4)
    v = reinterpret_cast<const float4*>(msk + (size_t)b * NCc)[i4];
  float vv[4] = {v.x, v.y, v.z, v.w};
  #pragma unroll
  for (int q = 0; q < 4; ++q) {
    float s1 = vv[q];
    unsigned bits = __float_as_uint(s1);
    bool pred = false;
    if (s1 > 0.0f) {
      int bin = (int)((bits - BIN_BASE) >> 12);
      pred = (bin >= Tbin);
    }
    ull bal = __ballot(pred);
    if (bal) {
      int nsel = __popcll(bal);
      int leader = __ffsll(bal) - 1;
      unsigned base = 0;
      if (lane == leader) base = atomicAdd(&cnt[b * 16], (unsigned)nsel);
      base = __shfl(base, leader);
      if (pred) {
        unsigned pos = base + (unsigned)__popcll(bal & ((1ULL << lane) - 1));
        if (pos < MCAP)
          keysg[(size_t)b * MCAP + pos] =
              ((ull)(0xFFFFFFFFu - bits) << 32) | (unsigned)(i4 * 4 + q);
      }
    }
  }
}

// ---------- kernel 5: bitonic sort of up to MCAP keys (1 block per image) ----------
__global__ void __launch_bounds__(1024)
sort_kernel(ull* __restrict__ keysg, const unsigned* __restrict__ cnt) {
  const int b = blockIdx.x, tid = threadIdx.x;
  __shared__ ull keys[MCAP];
  int S = (int)cnt[b * 16]; if (S > MCAP) S = MCAP;
  for (int i = tid; i < MCAP; i += 1024)
    keys[i] = (i < S) ? keysg[(size_t)b * MCAP + i] : ~0ULL;
  __syncthreads();
  for (int k = 2; k <= MCAP; k <<= 1) {
    for (int j = k >> 1; j > 0; j >>= 1) {
      for (int idx = tid; idx < MCAP; idx += 1024) {
        int l = idx ^ j;
        if (l > idx) {
          ull a = keys[idx], c = keys[l];
          bool asc = ((idx & k) == 0);
          if (asc ? (a > c) : (a < c)) { keys[idx] = c; keys[l] = a; }
        }
      }
      __syncthreads();
    }
  }
  for (int i = tid; i < MCAP; i += 1024)
    keysg[(size_t)b * MCAP + i] = keys[i];
}

// ---------- kernel 6: pairwise suppression bitmask (1 block per CU) ----------
__global__ void __launch_bounds__(1024)
mask_kernel(const ull* __restrict__ keysg,
            const unsigned* __restrict__ cnt,
            const float* __restrict__ offs,
            const float* __restrict__ deltas,
            const float* __restrict__ props,
            ull* __restrict__ maskm) {
  const int b = blockIdx.x >> 6;        // 64 blocks per image
  const int chunk = blockIdx.x & 63;    // rows [chunk*32, chunk*32+32)
  const int tid = threadIdx.x;
  __shared__ float cbx[MCAP][4];        // 32 KB, offset coords
  int S = (int)cnt[b * 16]; if (S > MCAP) S = MCAP;
  const float off_scale = offs[b];

  for (int s = tid; s < MCAP; s += 1024) {
    if (s < S) {
      ull key = keysg[(size_t)b * MCAP + s];
      unsigned i = (unsigned)key;
      float bb[4];
      decode_box(deltas, props, b, (int)i, bb);
      float o = (float)((int)(i % Cc) + 1) * off_scale;
      cbx[s][0] = bb[0] + o; cbx[s][1] = bb[1] + o;
      cbx[s][2] = bb[2] + o; cbx[s][3] = bb[3] + o;
    } else {
      cbx[s][0] = 0.f; cbx[s][1] = 0.f; cbx[s][2] = 0.f; cbx[s][3] = 0.f;
    }
  }
  __syncthreads();

  const int wv = tid >> 6;              // wave 0..15
  const int t = tid & 63;               // lane
  for (int q = wv; q < 32 * 32; q += 16) {
    const int r = q >> 5, w = q & 31;
    const int i = chunk * 32 + r;
    const int j = w * 64 + t;
    bool cond = false;
    if (i < S && j < S && j != i) {
      float ax1 = cbx[i][0], ay1 = cbx[i][1], ax2 = cbx[i][2], ay2 = cbx[i][3];
      float bx1 = cbx[j][0], by1 = cbx[j][1], bx2 = cbx[j][2], by2 = cbx[j][3];
      float ix1 = fmaxf(ax1, bx1), iy1 = fmaxf(ay1, by1);
      float ix2 = fminf(ax2, bx2), iy2 = fminf(ay2, by2);
      float inter = fmaxf(ix2 - ix1, 0.0f) * fmaxf(iy2 - iy1, 0.0f);
      float a1 = (ax2 - ax1) * (ay2 - ay1);
      float a2 = (bx2 - bx1) * (by2 - by1);
      cond = (inter / (a1 + a2 - inter)) > 0.5f;
    }
    ull word = __ballot(cond);
    if (t == 0 && i < S)
      maskm[((size_t)b * MCAP + i) * 32 + w] = word;
  }
}

// ---------- kernel 7: serial greedy scan over bitmask + output ----------
__global__ void __launch_bounds__(128)
scan_kernel(const ull* __restrict__ maskm,
            const ull* __restrict__ keysg,
            const unsigned* __restrict__ cnt,
            const float* __restrict__ deltas,
            const float* __restrict__ props,
            float* __restrict__ out) {
  const int b = blockIdx.x;
  const int tid = threadIdx.x;
  __shared__ int acc_list[DET];
  __shared__ int sh_acnt;
  int S = (int)cnt[b * 16]; if (S > MCAP) S = MCAP;

  if (tid < 64) {
    const int lane = tid & 63;
    const ull* mrow = maskm + (size_t)b * MCAP * 32 + (lane & 31);
    ull state = 0;
    ull pf[8];
    #pragma unroll
    for (int u = 0; u < 8; ++u) {
      int nj = u > MCAP - 1 ? MCAP - 1 : u;
      pf[u] = mrow[(size_t)nj * 32];
    }
    int acnt = 0;
    for (int j0 = 0; j0 < S && acnt < DET; j0 += 8) {
      ull cur[8];
      #pragma unroll
      for (int u = 0; u < 8; ++u) cur[u] = pf[u];
      #pragma unroll
      for (int u = 0; u < 8; ++u) {
        int nj = j0 + 8 + u; if (nj > MCAP - 1) nj = MCAP - 1;
        pf[u] = mrow[(size_t)nj * 32];
      }
      #pragma unroll
      for (int u = 0; u < 8; ++u) {
        const int j = j0 + u;
        ull aw = __shfl(state, j >> 6);
        bool alive = (j < S) && (acnt < DET) && !((aw >> (j & 63)) & 1ULL);
        if (alive) {
          state |= cur[u];
          if (lane == 0) acc_list[acnt] = j;
          ++acnt;
        }
      }
    }
    if (lane == 0) sh_acnt = acnt;
  }
  __syncthreads();

  const int acnt = sh_acnt;
  if (tid < DET) {
    float bb[4] = {0.f, 0.f, 0.f, 0.f};
    float sc = 0.f, lb = 0.f;
    if (tid < acnt) {
      const int j = acc_list[tid];
      ull key = keysg[(size_t)b * MCAP + j];
      unsigned bits = 0xFFFFFFFFu - (unsigned)(key >> 32);
      unsigned i = (unsigned)key;
      decode_box(deltas, props, b, (int)i, bb);
      sc = __uint_as_float(bits);
      lb = (float)((int)(i % Cc) + 1);
    }
    float* ob = out + (size_t)b * DET * 4 + tid * 4;
    ob[0] = bb[0]; ob[1] = bb[1]; ob[2] = bb[2]; ob[3] = bb[3];
    out[Bc * DET * 4 + b * DET + tid] = sc;
    out[Bc * DET * 4 + Bc * DET + b * DET + tid] = lb;
  }
}

// ---------- launch ----------
extern "C" void kernel_launch(void* const* d_in, const int* in_sizes, int n_in,
                              void* d_out, int out_size, void* d_ws, size_t ws_size,
                              hipStream_t stream) {
  const float* logits = (const float*)d_in[0];   // (B*N, 81)
  const float* deltas = (const float*)d_in[1];   // (B*N, 320)
  const float* props  = (const float*)d_in[2];   // (B, N, 4)
  float* out = (float*)d_out;

  char* ws = (char*)d_ws;
  unsigned* hist   = (unsigned*)(ws + 0);            // 262144 B
  unsigned* blkmax = (unsigned*)(ws + 262144);       // 20000 B
  float* rowmax    = (float*)(ws + 282144);          // 64000 B
  float* rowsum    = (float*)(ws + 346144);          // 64000 B
  float* msk       = (float*)(ws + 410144);          // 5,120,000 B
  ull* maskm       = (ull*)(ws + 410144);            // 2,097,152 B (overlays msk; written after msk's last read)
  ull* keysg       = (ull*)(ws + 5530144);           // 65536 B
  unsigned* cnt    = (unsigned*)(ws + 5595680);      // 256 B (4 counters, 64B apart)
  int* tbinp       = (int*)(ws + 5595936);           // 16 B
  float* offs      = (float*)(ws + 5595952);         // 16 B  -> total 5,595,968

  hipMemsetAsync(hist, 0, Bc * NBINS * 4, stream);

  row_stats_kernel<<<(Bc * Nc) / 4, 256, 0, stream>>>(logits, rowmax, rowsum);
  main_kernel<<<Bc * MBLK, 256, 0, stream>>>(logits, deltas, props,
                                             rowmax, rowsum, msk, hist, blkmax);
  tbin_kernel<<<Bc, 1024, 0, stream>>>(hist, blkmax, cnt, tbinp, offs);
  compact_kernel<<<Bc * CBLK, 256, 0, stream>>>(msk, tbinp, cnt, keysg);
  sort_kernel<<<Bc, 1024, 0, stream>>>(keysg, cnt);
  mask_kernel<<<Bc * 64, 1024, 0, stream>>>(keysg, cnt, offs, deltas, props, maskm);
  scan_kernel<<<Bc, 128, 0, stream>>>(maskm, keysg, cnt, deltas, props, out);
}

// Round 4
// 138.872 us; speedup vs baseline: 3.4837x; 1.1528x over previous
//
#include <hip/hip_runtime.h>
#include <math.h>

typedef unsigned long long ull;

#define Bc 4
#define Nc 4000
#define Cc 80
#define Lc 81
#define NCc (Nc * Cc)            // 320000 per image
#define NBINS 16384
#define NREP 8
#define MCAP 2048
#define TARGET 1024
#define DET 100
#define MBLK 1250                // main_kernel blocks per image
#define CBLK 157                 // compact blocks per image: ceil(40000/256)
#define BBOX_CLIPF 4.135166556742356f
#define BIN_BASE 0x3C000000u

// ---------- helpers ----------
__device__ __forceinline__ unsigned enc_f(float f) {
  unsigned u = __float_as_uint(f);
  return (u & 0x80000000u) ? ~u : (u | 0x80000000u);
}
__device__ __forceinline__ float dec_f(unsigned e) {
  unsigned u = (e & 0x80000000u) ? (e ^ 0x80000000u) : ~e;
  return __uint_as_float(u);
}

__device__ __forceinline__ void decode_box(const float* __restrict__ deltas,
                                           const float* __restrict__ props,
                                           int b, int i, float* o) {
  int n = i / Cc, c = i % Cc;
  int row = b * Nc + n;
  const float4 d = *reinterpret_cast<const float4*>(deltas + (size_t)row * (Cc * 4) + c * 4);
  const float4 p = *reinterpret_cast<const float4*>(props + (size_t)row * 4);
  float w = p.z - p.x, h = p.w - p.y;
  float cx = p.x + 0.5f * w, cy = p.y + 0.5f * h;
  float dw = fminf(d.z, BBOX_CLIPF), dh = fminf(d.w, BBOX_CLIPF);
  float pcx = d.x * w + cx, pcy = d.y * h + cy;
  float pw = expf(dw) * w, ph = expf(dh) * h;
  o[0] = pcx - 0.5f * pw;
  o[1] = pcy - 0.5f * ph;
  o[2] = pcx + 0.5f * pw;
  o[3] = pcy + 0.5f * ph;
}

// ---------- kernel 1: per-row softmax stats (one wave per row) ----------
__global__ void row_stats_kernel(const float* __restrict__ logits,
                                 float* __restrict__ rowmax,
                                 float* __restrict__ rowsum) {
  int wave = threadIdx.x >> 6;
  int lane = threadIdx.x & 63;
  int row = blockIdx.x * 4 + wave;
  if (row >= Bc * Nc) return;
  const float* p = logits + (size_t)row * Lc;
  float v1 = p[lane];
  float v2 = (lane < Lc - 64) ? p[64 + lane] : -INFINITY;
  float m = fmaxf(v1, v2);
  #pragma unroll
  for (int o = 32; o; o >>= 1) m = fmaxf(m, __shfl_xor(m, o));
  float s = expf(v1 - m) + ((lane < Lc - 64) ? expf(v2 - m) : 0.0f);
  #pragma unroll
  for (int o = 32; o; o >>= 1) s += __shfl_xor(s, o);
  if (lane == 0) { rowmax[row] = m; rowsum[row] = s; }
}

// ---------- kernel 2: scores, u16 bin map, replicated histogram, block max ----------
__global__ void main_kernel(const float* __restrict__ logits,
                            const float* __restrict__ deltas,
                            const float* __restrict__ props,
                            const float* __restrict__ rowmax,
                            const float* __restrict__ rowsum,
                            unsigned short* __restrict__ msk16,
                            unsigned* __restrict__ hist,
                            unsigned* __restrict__ blkmax) {
  int t = blockIdx.x * blockDim.x + threadIdx.x;   // 0 .. B*NC-1
  int b = t / NCc;
  int i = t % NCc;                                  // NC % 256 == 0 -> b uniform per block
  int n = i / Cc, c = i % Cc;
  int row = b * Nc + n;

  float lg = logits[(size_t)row * Lc + (c + 1)];
  float score = expf(lg - rowmax[row]) / rowsum[row];

  float bb[4];
  decode_box(deltas, props, b, i, bb);
  float area = (bb[3] - bb[1]) * (bb[2] - bb[0]);
  bool valid = (score > 0.01f) && (area > 0.1f);

  unsigned bits = __float_as_uint(score);
  int bin = (int)((bits - BIN_BASE) >> 12);
  bin = bin < 0 ? 0 : (bin > NBINS - 1 ? NBINS - 1 : bin);
  msk16[t] = valid ? (unsigned short)(bin + 1) : (unsigned short)0;

  if (valid) {
    int rep = blockIdx.x & (NREP - 1);
    atomicAdd(&hist[((rep * Bc + b) << 14) + bin], 1u);
  }

  float mc = fmaxf(fmaxf(bb[0], bb[1]), fmaxf(bb[2], bb[3]));
  unsigned e = enc_f(mc);
  #pragma unroll
  for (int o = 32; o; o >>= 1) {
    unsigned other = __shfl_xor(e, o);
    e = e > other ? e : other;
  }
  __shared__ unsigned wmax[4];
  if ((threadIdx.x & 63) == 0) wmax[threadIdx.x >> 6] = e;
  __syncthreads();
  if (threadIdx.x == 0) {
    unsigned m0 = wmax[0] > wmax[1] ? wmax[0] : wmax[1];
    unsigned m1 = wmax[2] > wmax[3] ? wmax[2] : wmax[3];
    blkmax[blockIdx.x] = m0 > m1 ? m0 : m1;
  }
}

// ---------- kernel 3: per-image off_scale + threshold bin (replica-summed) ----------
__global__ void __launch_bounds__(1024)
tbin_kernel(const unsigned* __restrict__ hist,
            const unsigned* __restrict__ blkmax,
            unsigned* __restrict__ cnt,
            int* __restrict__ tbinp,
            float* __restrict__ offs) {
  const int b = blockIdx.x, tid = threadIdx.x;
  __shared__ unsigned sc[1024];
  __shared__ int sh_Tbin;

  unsigned e = 0;
  for (int i = tid; i < MBLK; i += 1024) {
    unsigned v = blkmax[b * MBLK + i];
    if (v > e) e = v;
  }
  sc[tid] = e;
  __syncthreads();
  #pragma unroll
  for (int o = 512; o; o >>= 1) {
    if (tid < o) { unsigned v = sc[tid + o]; if (v > sc[tid]) sc[tid] = v; }
    __syncthreads();
  }
  if (tid == 0) {
    offs[b] = dec_f(sc[0]) + 1.0f;
    cnt[b * 16] = 0;
  }
  __syncthreads();

  // per-thread 16 bins summed over replicas, kept in registers
  unsigned hv[16];
  unsigned psum = 0;
  #pragma unroll
  for (int k = 0; k < 16; ++k) {
    int bin = tid * 16 + k;
    unsigned s = 0;
    #pragma unroll
    for (int r = 0; r < NREP; ++r) s += hist[((r * Bc + b) << 14) + bin];
    hv[k] = s;
    psum += s;
  }
  sc[tid] = psum;
  __syncthreads();
  for (int o = 1; o < 1024; o <<= 1) {
    unsigned v = (tid + o < 1024) ? sc[tid + o] : 0u;
    __syncthreads();
    sc[tid] += v;
    __syncthreads();
  }
  unsigned suf = sc[tid];
  unsigned sufn = (tid < 1023) ? sc[tid + 1] : 0u;
  if (tid == 0 && sc[0] < TARGET) sh_Tbin = 0;
  if (suf >= TARGET && sufn < TARGET) {              // unique crossing thread
    unsigned cum = sufn;
    int tb_found = -1;
    #pragma unroll
    for (int k = 15; k >= 0; --k) {
      if (tb_found < 0) {
        cum += hv[k];
        if (cum >= TARGET) tb_found = tid * 16 + k;
      }
    }
    int tb = tb_found;
    while (cum > MCAP) {                             // pathological-tie guard
      unsigned s = 0;
      for (int r = 0; r < NREP; ++r) s += hist[((r * Bc + b) << 14) + tb];
      cum -= s;
      ++tb;
    }
    sh_Tbin = tb;
  }
  __syncthreads();
  if (tid == 0) tbinp[b] = sh_Tbin;
}

// ---------- kernel 4: compaction (u16 bins, recompute exact score bits) ----------
__global__ void __launch_bounds__(256)
compact_kernel(const unsigned short* __restrict__ msk16,
               const float* __restrict__ logits,
               const float* __restrict__ rowmax,
               const float* __restrict__ rowsum,
               const int* __restrict__ tbinp,
               unsigned* __restrict__ cnt,
               ull* __restrict__ keysg) {
  const int b = blockIdx.x / CBLK;
  const int loc = blockIdx.x % CBLK;
  const int i8 = loc * 256 + threadIdx.x;
  const int lane = threadIdx.x & 63;
  const int Tbin = tbinp[b];

  uint4 v = make_uint4(0u, 0u, 0u, 0u);
  if (i8 < NCc / 8)
    v = reinterpret_cast<const uint4*>(msk16 + (size_t)b * NCc)[i8];
  unsigned ms[8];
  ms[0] = v.x & 0xFFFFu; ms[1] = v.x >> 16;
  ms[2] = v.y & 0xFFFFu; ms[3] = v.y >> 16;
  ms[4] = v.z & 0xFFFFu; ms[5] = v.z >> 16;
  ms[6] = v.w & 0xFFFFu; ms[7] = v.w >> 16;

  #pragma unroll
  for (int q = 0; q < 8; ++q) {
    unsigned m = ms[q];
    bool pred = (m != 0u) && ((int)(m - 1u) >= Tbin);
    ull bal = __ballot(pred);
    if (bal) {
      int nsel = __popcll(bal);
      int leader = __ffsll(bal) - 1;
      unsigned base = 0;
      if (lane == leader) base = atomicAdd(&cnt[b * 16], (unsigned)nsel);
      base = __shfl(base, leader);
      if (pred) {
        unsigned pos = base + (unsigned)__popcll(bal & ((1ULL << lane) - 1));
        if (pos < MCAP) {
          int i = i8 * 8 + q;
          int n = i / Cc, c = i % Cc;
          int row = b * Nc + n;
          float lg = logits[(size_t)row * Lc + (c + 1)];
          float score = expf(lg - rowmax[row]) / rowsum[row];  // identical expr -> identical bits
          unsigned bits = __float_as_uint(score);
          keysg[(size_t)b * MCAP + pos] =
              ((ull)(0xFFFFFFFFu - bits) << 32) | (unsigned)i;
        }
      }
    }
  }
}

// ---------- kernel 5: fused sort + pairwise suppression bitmask ----------
__global__ void __launch_bounds__(1024)
mask_sort_kernel(const ull* __restrict__ keysg,
                 ull* __restrict__ keysg2,
                 const unsigned* __restrict__ cnt,
                 const float* __restrict__ offs,
                 const float* __restrict__ deltas,
                 const float* __restrict__ props,
                 ull* __restrict__ maskm) {
  const int b = blockIdx.x >> 6;        // 64 blocks per image
  const int chunk = blockIdx.x & 63;    // rows [chunk*32, chunk*32+32)
  const int tid = threadIdx.x;
  __shared__ ull keys[MCAP];            // 16 KB
  __shared__ float cbx[MCAP][4];        // 32 KB, offset coords
  int S = (int)cnt[b * 16]; if (S > MCAP) S = MCAP;
  const float off_scale = offs[b];

  for (int i = tid; i < MCAP; i += 1024)
    keys[i] = (i < S) ? keysg[(size_t)b * MCAP + i] : ~0ULL;
  __syncthreads();

  // bitonic sort ascending (== score desc, index asc); identical in every block
  for (int k = 2; k <= MCAP; k <<= 1) {
    for (int j = k >> 1; j > 0; j >>= 1) {
      for (int idx = tid; idx < MCAP; idx += 1024) {
        int l = idx ^ j;
        if (l > idx) {
          ull a = keys[idx], c = keys[l];
          bool asc = ((idx & k) == 0);
          if (asc ? (a > c) : (a < c)) { keys[idx] = c; keys[l] = a; }
        }
      }
      __syncthreads();
    }
  }

  if (chunk == 0)                        // publish sorted keys for scan_kernel
    for (int i = tid; i < MCAP; i += 1024)
      keysg2[(size_t)b * MCAP + i] = keys[i];

  for (int s = tid; s < MCAP; s += 1024) {
    if (s < S) {
      unsigned i = (unsigned)keys[s];
      float bb[4];
      decode_box(deltas, props, b, (int)i, bb);
      float o = (float)((int)(i % Cc) + 1) * off_scale;
      cbx[s][0] = bb[0] + o; cbx[s][1] = bb[1] + o;
      cbx[s][2] = bb[2] + o; cbx[s][3] = bb[3] + o;
    } else {
      cbx[s][0] = 0.f; cbx[s][1] = 0.f; cbx[s][2] = 0.f; cbx[s][3] = 0.f;
    }
  }
  __syncthreads();

  const int wv = tid >> 6;              // wave 0..15
  const int t = tid & 63;               // lane
  for (int q = wv; q < 32 * 32; q += 16) {
    const int r = q >> 5, w = q & 31;
    const int i = chunk * 32 + r;
    const int j = w * 64 + t;
    bool cond = false;
    if (i < S && j < S && j != i) {
      float ax1 = cbx[i][0], ay1 = cbx[i][1], ax2 = cbx[i][2], ay2 = cbx[i][3];
      float bx1 = cbx[j][0], by1 = cbx[j][1], bx2 = cbx[j][2], by2 = cbx[j][3];
      float ix1 = fmaxf(ax1, bx1), iy1 = fmaxf(ay1, by1);
      float ix2 = fminf(ax2, bx2), iy2 = fminf(ay2, by2);
      float inter = fmaxf(ix2 - ix1, 0.0f) * fmaxf(iy2 - iy1, 0.0f);
      float a1 = (ax2 - ax1) * (ay2 - ay1);
      float a2 = (bx2 - bx1) * (by2 - by1);
      cond = (inter / (a1 + a2 - inter)) > 0.5f;
    }
    ull word = __ballot(cond);
    if (t == 0 && i < S)
      maskm[((size_t)b * MCAP + i) * 32 + w] = word;
  }
}

// ---------- kernel 6: serial greedy scan over bitmask + output ----------
__global__ void __launch_bounds__(128)
scan_kernel(const ull* __restrict__ maskm,
            const ull* __restrict__ keysg2,
            const unsigned* __restrict__ cnt,
            const float* __restrict__ deltas,
            const float* __restrict__ props,
            float* __restrict__ out) {
  const int b = blockIdx.x;
  const int tid = threadIdx.x;
  __shared__ int acc_list[DET];
  __shared__ int sh_acnt;
  int S = (int)cnt[b * 16]; if (S > MCAP) S = MCAP;

  if (tid < 64) {
    const int lane = tid & 63;
    const ull* mrow = maskm + (size_t)b * MCAP * 32 + (lane & 31);
    ull state = 0;
    ull pf[8];
    #pragma unroll
    for (int u = 0; u < 8; ++u) {
      int nj = u > MCAP - 1 ? MCAP - 1 : u;
      pf[u] = mrow[(size_t)nj * 32];
    }
    int acnt = 0;
    for (int j0 = 0; j0 < S && acnt < DET; j0 += 8) {
      ull cur[8];
      #pragma unroll
      for (int u = 0; u < 8; ++u) cur[u] = pf[u];
      #pragma unroll
      for (int u = 0; u < 8; ++u) {
        int nj = j0 + 8 + u; if (nj > MCAP - 1) nj = MCAP - 1;
        pf[u] = mrow[(size_t)nj * 32];
      }
      #pragma unroll
      for (int u = 0; u < 8; ++u) {
        const int j = j0 + u;
        ull aw = __shfl(state, j >> 6);
        bool alive = (j < S) && (acnt < DET) && !((aw >> (j & 63)) & 1ULL);
        if (alive) {
          state |= cur[u];
          if (lane == 0) acc_list[acnt] = j;
          ++acnt;
        }
      }
    }
    if (lane == 0) sh_acnt = acnt;
  }
  __syncthreads();

  const int acnt = sh_acnt;
  if (tid < DET) {
    float bb[4] = {0.f, 0.f, 0.f, 0.f};
    float sc = 0.f, lb = 0.f;
    if (tid < acnt) {
      const int j = acc_list[tid];
      ull key = keysg2[(size_t)b * MCAP + j];
      unsigned bits = 0xFFFFFFFFu - (unsigned)(key >> 32);
      unsigned i = (unsigned)key;
      decode_box(deltas, props, b, (int)i, bb);
      sc = __uint_as_float(bits);
      lb = (float)((int)(i % Cc) + 1);
    }
    float* ob = out + (size_t)b * DET * 4 + tid * 4;
    ob[0] = bb[0]; ob[1] = bb[1]; ob[2] = bb[2]; ob[3] = bb[3];
    out[Bc * DET * 4 + b * DET + tid] = sc;
    out[Bc * DET * 4 + Bc * DET + b * DET + tid] = lb;
  }
}

// ---------- launch ----------
extern "C" void kernel_launch(void* const* d_in, const int* in_sizes, int n_in,
                              void* d_out, int out_size, void* d_ws, size_t ws_size,
                              hipStream_t stream) {
  const float* logits = (const float*)d_in[0];   // (B*N, 81)
  const float* deltas = (const float*)d_in[1];   // (B*N, 320)
  const float* props  = (const float*)d_in[2];   // (B, N, 4)
  float* out = (float*)d_out;

  char* ws = (char*)d_ws;
  // hist: NREP*Bc*NBINS*4 = 2,097,152 B at [0 .. 2097152)
  unsigned* hist   = (unsigned*)(ws + 0);
  // keysg/keysg2 overlay hist (hist last read in tbin; keysg written in compact)
  ull* keysg       = (ull*)(ws + 0);                 // 65536 B
  ull* keysg2      = (ull*)(ws + 65536);             // 65536 B
  unsigned* blkmax = (unsigned*)(ws + 2097152);      // 20000 B
  float* rowmax    = (float*)(ws + 2117152);         // 64000 B
  float* rowsum    = (float*)(ws + 2181152);         // 64000 B
  unsigned short* msk16 = (unsigned short*)(ws + 2245152);  // 2,560,000 B
  // maskm overlays msk16 (msk16 last read in compact; maskm written in mask_sort)
  ull* maskm       = (ull*)(ws + 2245152);           // 2,097,152 B
  unsigned* cnt    = (unsigned*)(ws + 4805152);      // 256 B (4 counters, 64B apart)
  int* tbinp       = (int*)(ws + 4805408);           // 16 B
  float* offs      = (float*)(ws + 4805424);         // 16 B   -> total 4,805,440

  hipMemsetAsync(hist, 0, NREP * Bc * NBINS * 4, stream);

  row_stats_kernel<<<(Bc * Nc) / 4, 256, 0, stream>>>(logits, rowmax, rowsum);
  main_kernel<<<Bc * MBLK, 256, 0, stream>>>(logits, deltas, props,
                                             rowmax, rowsum, msk16, hist, blkmax);
  tbin_kernel<<<Bc, 1024, 0, stream>>>(hist, blkmax, cnt, tbinp, offs);
  compact_kernel<<<Bc * CBLK, 256, 0, stream>>>(msk16, logits, rowmax, rowsum,
                                                tbinp, cnt, keysg);
  mask_sort_kernel<<<Bc * 64, 1024, 0, stream>>>(keysg, keysg2, cnt, offs,
                                                 deltas, props, maskm);
  scan_kernel<<<Bc, 128, 0, stream>>>(maskm, keysg2, cnt, deltas, props, out);
}

// Round 5
// 102.792 us; speedup vs baseline: 4.7065x; 1.3510x over previous
//
#include <hip/hip_runtime.h>
#include <math.h>

typedef unsigned long long ull;

#define Bc 4
#define Nc 4000
#define Cc 80
#define Lc 81
#define NCc (Nc * Cc)            // 320000 per image
#define NBINS 16384
#define NREP 8
#define MCAP 2048
#define TARGET 1024
#define DET 100
#define MBLK 1000                // fused_main blocks per image (4 rows/block)
#define CBLK 157                 // compact blocks per image: ceil(40000/256)
#define BBOX_CLIPF 4.135166556742356f
#define BIN_BASE 0x3C000000u

// ---------- helpers ----------
__device__ __forceinline__ unsigned enc_f(float f) {
  unsigned u = __float_as_uint(f);
  return (u & 0x80000000u) ? ~u : (u | 0x80000000u);
}
__device__ __forceinline__ float dec_f(unsigned e) {
  unsigned u = (e & 0x80000000u) ? (e ^ 0x80000000u) : ~e;
  return __uint_as_float(u);
}

__device__ __forceinline__ void decode_box(const float* __restrict__ deltas,
                                           const float* __restrict__ props,
                                           int b, int i, float* o) {
  int n = i / Cc, c = i % Cc;
  int row = b * Nc + n;
  const float4 d = *reinterpret_cast<const float4*>(deltas + (size_t)row * (Cc * 4) + c * 4);
  const float4 p = *reinterpret_cast<const float4*>(props + (size_t)row * 4);
  float w = p.z - p.x, h = p.w - p.y;
  float cx = p.x + 0.5f * w, cy = p.y + 0.5f * h;
  float dw = fminf(d.z, BBOX_CLIPF), dh = fminf(d.w, BBOX_CLIPF);
  float pcx = d.x * w + cx, pcy = d.y * h + cy;
  float pw = expf(dw) * w, ph = expf(dh) * h;
  o[0] = pcx - 0.5f * pw;
  o[1] = pcy - 0.5f * ph;
  o[2] = pcx + 0.5f * pw;
  o[3] = pcy + 0.5f * ph;
}

// ---------- kernel 1: fused softmax + scores + bins + histogram + coord max ----------
// one wave per row of 81 logits / 80 channels
__global__ void __launch_bounds__(256)
fused_main(const float* __restrict__ logits,
           const float* __restrict__ deltas,
           const float* __restrict__ props,
           float* __restrict__ rowmax,
           float* __restrict__ rowsum,
           unsigned short* __restrict__ msk16,
           unsigned* __restrict__ hist,
           unsigned* __restrict__ blkmax) {
  const int wv = threadIdx.x >> 6, lane = threadIdx.x & 63;
  const int row = blockIdx.x * 4 + wv;            // 0..15999
  const int b = row / Nc;                          // uniform per block (4000 % 4 == 0)
  const int rep = blockIdx.x & (NREP - 1);

  const float* p = logits + (size_t)row * Lc;
  float v1 = p[lane];
  float v2 = (lane < 17) ? p[64 + lane] : -INFINITY;
  float m = fmaxf(v1, v2);
  #pragma unroll
  for (int o = 32; o; o >>= 1) m = fmaxf(m, __shfl_xor(m, o));
  float e1 = expf(v1 - m);
  float e2 = (lane < 17) ? expf(v2 - m) : 0.0f;
  float s = e1 + e2;
  #pragma unroll
  for (int o = 32; o; o >>= 1) s += __shfl_xor(s, o);
  if (lane == 0) { rowmax[row] = m; rowsum[row] = s; }

  // channel c1 = lane needs exp(p[lane+1]-m); c2 = 64+lane needs exp(p[65+lane]-m)
  float e2_0 = __shfl(e2, 0);
  float sd1 = __shfl_down(e1, 1);
  float sc1e = (lane == 63) ? e2_0 : sd1;
  float sc2e = __shfl_down(e2, 1);                 // valid for lane<16
  float score1 = sc1e / s;
  float score2 = sc2e / s;

  const float* drow = deltas + (size_t)row * (Cc * 4);
  const float4 pr = *reinterpret_cast<const float4*>(props + (size_t)row * 4);
  float w = pr.z - pr.x, h = pr.w - pr.y;
  float cx = pr.x + 0.5f * w, cy = pr.y + 0.5f * h;

  // ---- pass 1: c = lane (0..63) ----
  float4 d1 = *reinterpret_cast<const float4*>(drow + lane * 4);
  float dw1 = fminf(d1.z, BBOX_CLIPF), dh1 = fminf(d1.w, BBOX_CLIPF);
  float pcx1 = d1.x * w + cx, pcy1 = d1.y * h + cy;
  float pw1 = expf(dw1) * w, ph1 = expf(dh1) * h;
  float b10 = pcx1 - 0.5f * pw1, b11 = pcy1 - 0.5f * ph1;
  float b12 = pcx1 + 0.5f * pw1, b13 = pcy1 + 0.5f * ph1;
  float area1 = (b13 - b11) * (b12 - b10);
  bool valid1 = (score1 > 0.01f) && (area1 > 0.1f);
  unsigned bits1 = __float_as_uint(score1);
  int bin1 = (int)((bits1 - BIN_BASE) >> 12);
  bin1 = bin1 < 0 ? 0 : (bin1 > NBINS - 1 ? NBINS - 1 : bin1);
  msk16[(size_t)row * Cc + lane] = valid1 ? (unsigned short)(bin1 + 1) : (unsigned short)0;
  if (valid1) atomicAdd(&hist[((rep * Bc + b) << 14) + bin1], 1u);
  float mc = fmaxf(fmaxf(b10, b11), fmaxf(b12, b13));

  // ---- pass 2: c = 64 + lane (lane < 16) ----
  if (lane < 16) {
    float4 d2 = *reinterpret_cast<const float4*>(drow + (64 + lane) * 4);
    float dw2 = fminf(d2.z, BBOX_CLIPF), dh2 = fminf(d2.w, BBOX_CLIPF);
    float pcx2 = d2.x * w + cx, pcy2 = d2.y * h + cy;
    float pw2 = expf(dw2) * w, ph2 = expf(dh2) * h;
    float b20 = pcx2 - 0.5f * pw2, b21 = pcy2 - 0.5f * ph2;
    float b22 = pcx2 + 0.5f * pw2, b23 = pcy2 + 0.5f * ph2;
    float area2 = (b23 - b21) * (b22 - b20);
    bool valid2 = (score2 > 0.01f) && (area2 > 0.1f);
    unsigned bits2 = __float_as_uint(score2);
    int bin2 = (int)((bits2 - BIN_BASE) >> 12);
    bin2 = bin2 < 0 ? 0 : (bin2 > NBINS - 1 ? NBINS - 1 : bin2);
    msk16[(size_t)row * Cc + 64 + lane] = valid2 ? (unsigned short)(bin2 + 1) : (unsigned short)0;
    if (valid2) atomicAdd(&hist[((rep * Bc + b) << 14) + bin2], 1u);
    mc = fmaxf(mc, fmaxf(fmaxf(b20, b21), fmaxf(b22, b23)));
  }

  // block-level coordinate max
  unsigned e = enc_f(mc);
  #pragma unroll
  for (int o = 32; o; o >>= 1) {
    unsigned other = __shfl_xor(e, o);
    e = e > other ? e : other;
  }
  __shared__ unsigned wmax[4];
  if (lane == 0) wmax[wv] = e;
  __syncthreads();
  if (threadIdx.x == 0) {
    unsigned m0 = wmax[0] > wmax[1] ? wmax[0] : wmax[1];
    unsigned m1 = wmax[2] > wmax[3] ? wmax[2] : wmax[3];
    blkmax[blockIdx.x] = m0 > m1 ? m0 : m1;
  }
}

// ---------- kernel 2: per-image off_scale + threshold bin (replica-summed) ----------
__global__ void __launch_bounds__(1024)
tbin_kernel(const unsigned* __restrict__ hist,
            const unsigned* __restrict__ blkmax,
            unsigned* __restrict__ cnt,
            int* __restrict__ tbinp,
            float* __restrict__ offs) {
  const int b = blockIdx.x, tid = threadIdx.x;
  __shared__ unsigned sc[1024];
  __shared__ int sh_Tbin;

  unsigned e = 0;
  if (tid < MBLK) e = blkmax[b * MBLK + tid];
  sc[tid] = e;
  __syncthreads();
  #pragma unroll
  for (int o = 512; o; o >>= 1) {
    if (tid < o) { unsigned v = sc[tid + o]; if (v > sc[tid]) sc[tid] = v; }
    __syncthreads();
  }
  if (tid == 0) {
    offs[b] = dec_f(sc[0]) + 1.0f;
    cnt[b * 16] = 0;
  }
  __syncthreads();

  unsigned hv[16];
  unsigned psum = 0;
  #pragma unroll
  for (int k = 0; k < 16; ++k) {
    int bin = tid * 16 + k;
    unsigned s = 0;
    #pragma unroll
    for (int r = 0; r < NREP; ++r) s += hist[((r * Bc + b) << 14) + bin];
    hv[k] = s;
    psum += s;
  }
  sc[tid] = psum;
  __syncthreads();
  for (int o = 1; o < 1024; o <<= 1) {
    unsigned v = (tid + o < 1024) ? sc[tid + o] : 0u;
    __syncthreads();
    sc[tid] += v;
    __syncthreads();
  }
  unsigned suf = sc[tid];
  unsigned sufn = (tid < 1023) ? sc[tid + 1] : 0u;
  if (tid == 0 && sc[0] < TARGET) sh_Tbin = 0;
  if (suf >= TARGET && sufn < TARGET) {              // unique crossing thread
    unsigned cum = sufn;
    int tb_found = -1;
    #pragma unroll
    for (int k = 15; k >= 0; --k) {
      if (tb_found < 0) {
        cum += hv[k];
        if (cum >= TARGET) tb_found = tid * 16 + k;
      }
    }
    int tb = tb_found;
    while (cum > MCAP) {                             // pathological-tie guard
      unsigned s = 0;
      for (int r = 0; r < NREP; ++r) s += hist[((r * Bc + b) << 14) + tb];
      cum -= s;
      ++tb;
    }
    sh_Tbin = tb;
  }
  __syncthreads();
  if (tid == 0) tbinp[b] = sh_Tbin;
}

// ---------- kernel 3: compaction (u16 bins, recompute exact score bits) ----------
__global__ void __launch_bounds__(256)
compact_kernel(const unsigned short* __restrict__ msk16,
               const float* __restrict__ logits,
               const float* __restrict__ rowmax,
               const float* __restrict__ rowsum,
               const int* __restrict__ tbinp,
               unsigned* __restrict__ cnt,
               ull* __restrict__ keysg) {
  const int b = blockIdx.x / CBLK;
  const int loc = blockIdx.x % CBLK;
  const int i8 = loc * 256 + threadIdx.x;
  const int lane = threadIdx.x & 63;
  const int Tbin = tbinp[b];

  uint4 v = make_uint4(0u, 0u, 0u, 0u);
  if (i8 < NCc / 8)
    v = reinterpret_cast<const uint4*>(msk16 + (size_t)b * NCc)[i8];
  unsigned ms[8];
  ms[0] = v.x & 0xFFFFu; ms[1] = v.x >> 16;
  ms[2] = v.y & 0xFFFFu; ms[3] = v.y >> 16;
  ms[4] = v.z & 0xFFFFu; ms[5] = v.z >> 16;
  ms[6] = v.w & 0xFFFFu; ms[7] = v.w >> 16;

  #pragma unroll
  for (int q = 0; q < 8; ++q) {
    unsigned m = ms[q];
    bool pred = (m != 0u) && ((int)(m - 1u) >= Tbin);
    ull bal = __ballot(pred);
    if (bal) {
      int nsel = __popcll(bal);
      int leader = __ffsll(bal) - 1;
      unsigned base = 0;
      if (lane == leader) base = atomicAdd(&cnt[b * 16], (unsigned)nsel);
      base = __shfl(base, leader);
      if (pred) {
        unsigned pos = base + (unsigned)__popcll(bal & ((1ULL << lane) - 1));
        if (pos < MCAP) {
          int i = i8 * 8 + q;
          int n = i / Cc, c = i % Cc;
          int row = b * Nc + n;
          float lg = logits[(size_t)row * Lc + (c + 1)];
          float score = expf(lg - rowmax[row]) / rowsum[row];  // identical expr -> identical bits
          unsigned bits = __float_as_uint(score);
          keysg[(size_t)b * MCAP + pos] =
              ((ull)(0xFFFFFFFFu - bits) << 32) | (unsigned)i;
        }
      }
    }
  }
}

// ---------- kernel 4: counting-rank "sort" + sorted box scatter ----------
__global__ void __launch_bounds__(1024)
rank_kernel(const ull* __restrict__ keysg,
            const unsigned* __restrict__ cnt,
            const float* __restrict__ offs,
            const float* __restrict__ deltas,
            const float* __restrict__ props,
            ull* __restrict__ keysg2,
            float4* __restrict__ boxesg) {
  const int b = blockIdx.x >> 6;        // 64 blocks per image
  const int chunk = blockIdx.x & 63;    // rows [chunk*32, chunk*32+32)
  const int tid = threadIdx.x;
  const int wv = tid >> 6, lane = tid & 63;
  __shared__ ull keys[MCAP];            // 16 KB
  int S = (int)cnt[b * 16]; if (S > MCAP) S = MCAP;
  const float off_scale = offs[b];

  for (int i = tid; i < MCAP; i += 1024)
    keys[i] = keysg[(size_t)b * MCAP + i];     // >=S entries garbage, never compared
  __syncthreads();

  #pragma unroll
  for (int p = 0; p < 2; ++p) {
    const int r = chunk * 32 + wv * 2 + p;
    if (r < S) {
      const ull kr = keys[r];
      int rank = 0;
      #pragma unroll 8
      for (int step = 0; step < 32; ++step) {
        int j = step * 64 + lane;
        bool pred = (j < S) && (keys[j] < kr);
        rank += __popcll(__ballot(pred));
      }
      if (lane == 0) {
        keysg2[(size_t)b * MCAP + rank] = kr;
        unsigned i = (unsigned)kr;
        float bb[4];
        decode_box(deltas, props, b, (int)i, bb);
        float o = (float)((int)(i % Cc) + 1) * off_scale;
        boxesg[(size_t)b * MCAP + rank] =
            make_float4(bb[0] + o, bb[1] + o, bb[2] + o, bb[3] + o);
      }
    }
  }
}

// ---------- kernel 5: pairwise suppression bitmask (sorted boxes from global) ----------
__global__ void __launch_bounds__(1024)
mask_kernel(const float4* __restrict__ boxesg,
            const unsigned* __restrict__ cnt,
            ull* __restrict__ maskm) {
  const int b = blockIdx.x >> 6;        // 64 blocks per image
  const int chunk = blockIdx.x & 63;    // rows [chunk*32, chunk*32+32)
  const int tid = threadIdx.x;
  __shared__ float4 cbx[MCAP];          // 32 KB
  int S = (int)cnt[b * 16]; if (S > MCAP) S = MCAP;

  for (int i = tid; i < MCAP; i += 1024)
    cbx[i] = boxesg[(size_t)b * MCAP + i];     // >=S entries garbage, never used
  __syncthreads();

  const int wv = tid >> 6;              // wave 0..15
  const int t = tid & 63;               // lane
  for (int q = wv; q < 32 * 32; q += 16) {
    const int r = q >> 5, w = q & 31;
    const int i = chunk * 32 + r;
    const int j = w * 64 + t;
    bool cond = false;
    if (i < S && j < S && j != i) {
      float4 bi = cbx[i];
      float4 bj = cbx[j];
      float ix1 = fmaxf(bi.x, bj.x), iy1 = fmaxf(bi.y, bj.y);
      float ix2 = fminf(bi.z, bj.z), iy2 = fminf(bi.w, bj.w);
      float inter = fmaxf(ix2 - ix1, 0.0f) * fmaxf(iy2 - iy1, 0.0f);
      float a1 = (bi.z - bi.x) * (bi.w - bi.y);
      float a2 = (bj.z - bj.x) * (bj.w - bj.y);
      cond = (inter / (a1 + a2 - inter)) > 0.5f;
    }
    ull word = __ballot(cond);
    if (t == 0 && i < S)
      maskm[((size_t)b * MCAP + i) * 32 + w] = word;
  }
}

// ---------- kernel 6: serial greedy scan over bitmask + output ----------
__global__ void __launch_bounds__(128)
scan_kernel(const ull* __restrict__ maskm,
            const ull* __restrict__ keysg2,
            const unsigned* __restrict__ cnt,
            const float* __restrict__ deltas,
            const float* __restrict__ props,
            float* __restrict__ out) {
  const int b = blockIdx.x;
  const int tid = threadIdx.x;
  __shared__ int acc_list[DET];
  __shared__ int sh_acnt;
  int S = (int)cnt[b * 16]; if (S > MCAP) S = MCAP;

  if (tid < 64) {
    const int lane = tid & 63;
    const ull* mrow = maskm + (size_t)b * MCAP * 32 + (lane & 31);
    ull state = 0;
    ull pf[8];
    #pragma unroll
    for (int u = 0; u < 8; ++u) {
      int nj = u > MCAP - 1 ? MCAP - 1 : u;
      pf[u] = mrow[(size_t)nj * 32];
    }
    int acnt = 0;
    for (int j0 = 0; j0 < S && acnt < DET; j0 += 8) {
      ull cur[8];
      #pragma unroll
      for (int u = 0; u < 8; ++u) cur[u] = pf[u];
      #pragma unroll
      for (int u = 0; u < 8; ++u) {
        int nj = j0 + 8 + u; if (nj > MCAP - 1) nj = MCAP - 1;
        pf[u] = mrow[(size_t)nj * 32];
      }
      #pragma unroll
      for (int u = 0; u < 8; ++u) {
        const int j = j0 + u;
        ull aw = __shfl(state, j >> 6);
        bool alive = (j < S) && (acnt < DET) && !((aw >> (j & 63)) & 1ULL);
        if (alive) {
          state |= cur[u];
          if (lane == 0) acc_list[acnt] = j;
          ++acnt;
        }
      }
    }
    if (lane == 0) sh_acnt = acnt;
  }
  __syncthreads();

  const int acnt = sh_acnt;
  if (tid < DET) {
    float bb[4] = {0.f, 0.f, 0.f, 0.f};
    float sc = 0.f, lb = 0.f;
    if (tid < acnt) {
      const int j = acc_list[tid];
      ull key = keysg2[(size_t)b * MCAP + j];
      unsigned bits = 0xFFFFFFFFu - (unsigned)(key >> 32);
      unsigned i = (unsigned)key;
      decode_box(deltas, props, b, (int)i, bb);
      sc = __uint_as_float(bits);
      lb = (float)((int)(i % Cc) + 1);
    }
    float* ob = out + (size_t)b * DET * 4 + tid * 4;
    ob[0] = bb[0]; ob[1] = bb[1]; ob[2] = bb[2]; ob[3] = bb[3];
    out[Bc * DET * 4 + b * DET + tid] = sc;
    out[Bc * DET * 4 + Bc * DET + b * DET + tid] = lb;
  }
}

// ---------- launch ----------
extern "C" void kernel_launch(void* const* d_in, const int* in_sizes, int n_in,
                              void* d_out, int out_size, void* d_ws, size_t ws_size,
                              hipStream_t stream) {
  const float* logits = (const float*)d_in[0];   // (B*N, 81)
  const float* deltas = (const float*)d_in[1];   // (B*N, 320)
  const float* props  = (const float*)d_in[2];   // (B, N, 4)
  float* out = (float*)d_out;

  char* ws = (char*)d_ws;
  // hist: NREP*Bc*NBINS*4 = 2,097,152 B at [0 .. 2097152)
  unsigned* hist   = (unsigned*)(ws + 0);
  // overlays on hist (hist last read in tbin; these written in compact/rank after)
  ull* keysg       = (ull*)(ws + 0);                 // 65,536 B
  ull* keysg2      = (ull*)(ws + 65536);             // 65,536 B
  float4* boxesg   = (float4*)(ws + 131072);         // 131,072 B
  unsigned* blkmax = (unsigned*)(ws + 2097152);      // Bc*MBLK*4 = 16,000 B
  float* rowmax    = (float*)(ws + 2113152);         // 64,000 B
  float* rowsum    = (float*)(ws + 2177152);         // 64,000 B
  unsigned short* msk16 = (unsigned short*)(ws + 2241152);  // 2,560,000 B
  // maskm overlays msk16 (msk16 last read in compact; maskm written in mask_kernel)
  ull* maskm       = (ull*)(ws + 2241152);           // 2,097,152 B
  unsigned* cnt    = (unsigned*)(ws + 4801152);      // 256 B (4 counters, 64B apart)
  int* tbinp       = (int*)(ws + 4801408);           // 16 B
  float* offs      = (float*)(ws + 4801424);         // 16 B  -> total 4,801,440

  hipMemsetAsync(hist, 0, NREP * Bc * NBINS * 4, stream);

  fused_main<<<Bc * MBLK, 256, 0, stream>>>(logits, deltas, props,
                                            rowmax, rowsum, msk16, hist, blkmax);
  tbin_kernel<<<Bc, 1024, 0, stream>>>(hist, blkmax, cnt, tbinp, offs);
  compact_kernel<<<Bc * CBLK, 256, 0, stream>>>(msk16, logits, rowmax, rowsum,
                                                tbinp, cnt, keysg);
  rank_kernel<<<Bc * 64, 1024, 0, stream>>>(keysg, cnt, offs, deltas, props,
                                            keysg2, boxesg);
  mask_kernel<<<Bc * 64, 1024, 0, stream>>>(boxesg, cnt, maskm);
  scan_kernel<<<Bc, 128, 0, stream>>>(maskm, keysg2, cnt, deltas, props, out);
}